// Round 5
// baseline (182.086 us; speedup 1.0000x reference)
//
#include <hip/hip_runtime.h>
#include <cstdint>

#define BATCH  4
#define SLEN   4096
#define FDIM   64
#define KDIM   32
#define KSPLIT 8
#define CHUNK  (SLEN / KSPLIT)   // 512

typedef __attribute__((ext_vector_type(8))) short bf16x8;
typedef __attribute__((ext_vector_type(4))) float f32x4;

static __device__ __forceinline__ short f2bf(float f) {
    union { float f; unsigned u; } v; v.f = f;
    unsigned r = v.u + 0x7fffu + ((v.u >> 16) & 1u);   // RNE
    return (short)(r >> 16);
}
static __device__ __forceinline__ float bf2f(short s) {
    union { unsigned u; float f; } v;
    v.u = ((unsigned)(unsigned short)s) << 16;
    return v.f;
}
// pack2bf(a,b) -> uint, low short = bf16(a), high short = bf16(b), RNE.
static __device__ __forceinline__ unsigned pack2bf(float a, float b) {
    union { float f; unsigned u; } x, y; x.f = a; y.f = b;
    unsigned ra = x.u + 0x7fffu + ((x.u >> 16) & 1u);
    unsigned rb = y.u + 0x7fffu + ((y.u >> 16) & 1u);
    return __builtin_amdgcn_perm(rb, ra, 0x07060302u);  // {rb.hi, ra.hi}
}

// ---------------------------------------------------------------------------
// M -> bf16 hi + lo (Dekker split), float4 -> 2x ushort4.
// ---------------------------------------------------------------------------
__global__ __launch_bounds__(256) void split_m(const float4* __restrict__ M4,
                                               ushort4* __restrict__ H4,
                                               ushort4* __restrict__ L4) {
    int i = blockIdx.x * 256 + threadIdx.x;      // [0, B*S*32/4)
    float4 m = M4[i];
    ushort4 h, l;
    h.x = (unsigned short)f2bf(m.x); l.x = (unsigned short)f2bf(m.x - bf2f((short)h.x));
    h.y = (unsigned short)f2bf(m.y); l.y = (unsigned short)f2bf(m.y - bf2f((short)h.y));
    h.z = (unsigned short)f2bf(m.z); l.z = (unsigned short)f2bf(m.z - bf2f((short)h.z));
    h.w = (unsigned short)f2bf(m.w); l.w = (unsigned short)f2bf(m.w - bf2f((short)h.w));
    H4[i] = h; L4[i] = l;
}

// ---------------------------------------------------------------------------
// Fused: V = X @ W (fp32 out) AND Vt[b][f][s0+perm(c)] = bf16(V) transpose.
// perm within each 32-group: p = 2*(c&15) + ((c>>4)&1)  (matches packed-pair
// P staging order in attn_mfma so PV B-frags stay contiguous b128 loads).
// Block: 64 s-rows of one batch, 256 threads.
// ---------------------------------------------------------------------------
__global__ __launch_bounds__(256) void xw_transpose(const float* __restrict__ X,
                                                    const float4* __restrict__ W4,
                                                    float4* __restrict__ V4,
                                                    short* __restrict__ Vt) {
    __shared__ float t[64][65];
    const int b  = blockIdx.y;
    const int s0 = blockIdx.x * 64;
    const int o4 = threadIdx.x & 15;             // float4 index over f
    const int rq = threadIdx.x >> 4;             // 0..15
#pragma unroll
    for (int half = 0; half < 4; ++half) {
        int r = half * 16 + rq;
        const float* __restrict__ xr = X + ((size_t)b * SLEN + s0 + r) * FDIM;
        float4 acc = make_float4(0.f, 0.f, 0.f, 0.f);
#pragma unroll
        for (int f = 0; f < FDIM; ++f) {
            float4 w = W4[f * 16 + o4];
            float  x = xr[f];
            acc.x = fmaf(x, w.x, acc.x);
            acc.y = fmaf(x, w.y, acc.y);
            acc.z = fmaf(x, w.z, acc.z);
            acc.w = fmaf(x, w.w, acc.w);
        }
        V4[((size_t)b * SLEN + s0 + r) * 16 + o4] = acc;
        t[r][o4 * 4 + 0] = acc.x;
        t[r][o4 * 4 + 1] = acc.y;
        t[r][o4 * 4 + 2] = acc.z;
        t[r][o4 * 4 + 3] = acc.w;
    }
    __syncthreads();
    const int c0 = threadIdx.x & 63;
    const int r0 = threadIdx.x >> 6;
    const int pc = (c0 & 32) | (((c0 & 15) << 1) | ((c0 >> 4) & 1));
#pragma unroll
    for (int i = 0; i < 16; ++i) {
        int f = r0 + i * 4;
        Vt[((size_t)b * FDIM + f) * SLEN + s0 + pc] = f2bf(t[c0][f]);
    }
}

// ---------------------------------------------------------------------------
// Attention partials, MFMA, 64 keys/iteration, XCD-swizzled grid.
// Grid: 2048 1-D blocks. bid -> (g = slab (b,ks), i = q-tile) such that all
// 64 blocks of one slab share one XCD (assumes XCD = bid % 8): per-XCD L2
// working set ~512 KB instead of ~16 MB.
// ---------------------------------------------------------------------------
__global__ __launch_bounds__(256, 4) void attn_mfma(const short* __restrict__ Mhi,
                                                    const short* __restrict__ Mlo,
                                                    const short* __restrict__ Vt,
                                                    float* __restrict__ accP,
                                                    float* __restrict__ lP) {
    const int bid  = blockIdx.x;
    const int xcd  = bid & 7;
    const int slot = bid >> 3;
    const int g    = xcd + 8 * (slot >> 6);      // slab id [0,32)
    const int qt   = slot & 63;                  // q-tile  [0,64)
    const int b    = g >> 3;
    const int ks   = g & 7;

    const int tid  = threadIdx.x;
    const int wave = tid >> 6;
    const int lane = tid & 63;
    const int col  = lane & 15;
    const int quad = lane >> 4;
    const int qbase = qt * 64 + wave * 16;
    const int k0    = ks * CHUNK;

    const short* __restrict__ Mbh = Mhi + (size_t)b * SLEN * KDIM;
    const short* __restrict__ Mbl = Mlo + (size_t)b * SLEN * KDIM;
    const short* __restrict__ Vb  = Vt  + (size_t)b * FDIM * SLEN;

    bf16x8 Ah = *(const bf16x8*)(Mbh + (qbase + col) * KDIM + quad * 8);
    bf16x8 Al = *(const bf16x8*)(Mbl + (qbase + col) * KDIM + quad * 8);

    f32x4 accf[4];
#pragma unroll
    for (int fg = 0; fg < 4; ++fg) accf[fg] = (f32x4){0.f, 0.f, 0.f, 0.f};
    float lacc[4] = {0.f, 0.f, 0.f, 0.f};

    __shared__ unsigned plds[4][2][16 * 20];     // 10240 B
    unsigned* __restrict__ pg0 = plds[wave][0];
    unsigned* __restrict__ pg1 = plds[wave][1];

#pragma unroll 1
    for (int kt = k0; kt < k0 + CHUNK; kt += 64) {
        // ---- issue all global loads for this iteration up front ----
        bf16x8 Bh[4], Bl[4], Vv[4][2];
#pragma unroll
        for (int t = 0; t < 4; ++t) {
            int off = (kt + 16 * t + col) * KDIM + quad * 8;
            Bh[t] = *(const bf16x8*)(Mbh + off);
            Bl[t] = *(const bf16x8*)(Mbl + off);
        }
#pragma unroll
        for (int fg = 0; fg < 4; ++fg) {
            int vo = (fg * 16 + col) * SLEN + kt + quad * 8;
            Vv[fg][0] = *(const bf16x8*)(Vb + vo);
            Vv[fg][1] = *(const bf16x8*)(Vb + vo + 32);
        }
        __builtin_amdgcn_sched_barrier(0);       // keep loads issued here

        // ---- QK: 4 tiles, depth-2 (hi*hi parallel to lo-chain) ----
        f32x4 ca[4], cb[4];
#pragma unroll
        for (int t = 0; t < 4; ++t) {
            f32x4 z = (f32x4){0.f, 0.f, 0.f, 0.f};
            ca[t] = __builtin_amdgcn_mfma_f32_16x16x32_bf16(Ah, Bh[t], z, 0, 0, 0);
            cb[t] = __builtin_amdgcn_mfma_f32_16x16x32_bf16(Al, Bh[t], z, 0, 0, 0);
            cb[t] = __builtin_amdgcn_mfma_f32_16x16x32_bf16(Ah, Bl[t], cb[t], 0, 0, 0);
        }

        // ---- exp(relu(s)), pack pairs, stage both 32-key groups ----
#pragma unroll
        for (int j = 0; j < 4; ++j) {
            float p00 = __expf(fmaxf(ca[0][j] + cb[0][j], 0.f));
            float p01 = __expf(fmaxf(ca[1][j] + cb[1][j], 0.f));
            float p10 = __expf(fmaxf(ca[2][j] + cb[2][j], 0.f));
            float p11 = __expf(fmaxf(ca[3][j] + cb[3][j], 0.f));
            lacc[j] += (p00 + p01) + (p10 + p11);
            pg0[(quad * 4 + j) * 20 + col] = pack2bf(p00, p01);
            pg1[(quad * 4 + j) * 20 + col] = pack2bf(p10, p11);
        }

        // ---- P A-frags (same-wave LDS RAW; one lgkm wait covers both) ----
        bf16x8 Pa0 = *(const bf16x8*)((const short*)pg0 + col * 40 + quad * 8);
        bf16x8 Pa1 = *(const bf16x8*)((const short*)pg1 + col * 40 + quad * 8);

        // ---- PV: 4 chains of depth 2 ----
#pragma unroll
        for (int fg = 0; fg < 4; ++fg) {
            accf[fg] = __builtin_amdgcn_mfma_f32_16x16x32_bf16(Pa0, Vv[fg][0],
                                                               accf[fg], 0, 0, 0);
            accf[fg] = __builtin_amdgcn_mfma_f32_16x16x32_bf16(Pa1, Vv[fg][1],
                                                               accf[fg], 0, 0, 0);
        }
    }

    // Epilogue: partial O (C-layout) + partial l (reduce 16 cols per row).
#pragma unroll
    for (int j = 0; j < 4; ++j) {
        int q = qbase + quad * 4 + j;
        size_t base = ((size_t)b * SLEN + q) * KSPLIT + ks;
        float* __restrict__ op = accP + base * FDIM;
#pragma unroll
        for (int fg = 0; fg < 4; ++fg)
            op[fg * 16 + col] = accf[fg][j];
        float lv = lacc[j];
#pragma unroll
        for (int m = 1; m < 16; m <<= 1) lv += __shfl_xor(lv, m);
        if (col == 0) lP[base] = lv;
    }
}

// ---------------------------------------------------------------------------
// out = V + (sum acc_i)/(sum l_i) + bias, float4.
// ---------------------------------------------------------------------------
__global__ __launch_bounds__(256) void combine_kernel(const float4* __restrict__ V4,
                                                      const float4* __restrict__ accP4,
                                                      const float* __restrict__ lP,
                                                      const float4* __restrict__ bias4,
                                                      float4* __restrict__ out4) {
    int i  = blockIdx.x * 256 + threadIdx.x;     // [0, B*S*16)
    int o4 = i & 15;
    int row = i >> 4;
    float nx = 0.f, ny = 0.f, nz = 0.f, nw = 0.f, den = 0.f;
#pragma unroll
    for (int k = 0; k < KSPLIT; ++k) {
        float4 a = accP4[((size_t)row * KSPLIT + k) * 16 + o4];
        nx += a.x; ny += a.y; nz += a.z; nw += a.w;
        den += lP[(size_t)row * KSPLIT + k];
    }
    float r = 1.f / den;
    float4 v = V4[i];
    float4 bb = bias4[o4];
    float4 o;
    o.x = v.x + nx * r + bb.x;
    o.y = v.y + ny * r + bb.y;
    o.z = v.z + nz * r + bb.z;
    o.w = v.w + nw * r + bb.w;
    out4[i] = o;
}

// ---------------------------------------------------------------------------
extern "C" void kernel_launch(void* const* d_in, const int* in_sizes, int n_in,
                              void* d_out, int out_size, void* d_ws, size_t ws_size,
                              hipStream_t stream) {
    const float* X    = (const float*)d_in[0];   // [4,4096,64]
    const float* M    = (const float*)d_in[1];   // [4,4096,32]
    const float* W    = (const float*)d_in[2];   // [64,64]
    const float* bias = (const float*)d_in[3];   // [64]
    float* out = (float*)d_out;                  // [4,4096,64]

    const size_t vElems = (size_t)BATCH * SLEN * FDIM;   // 1,048,576
    const size_t mElems = (size_t)BATCH * SLEN * KDIM;   //   524,288
    const size_t rows   = (size_t)BATCH * SLEN;          //    16,384

    float* Vf   = (float*)d_ws;
    float* accP = Vf + vElems;
    float* lP   = accP + vElems * KSPLIT;
    short* Mhi  = (short*)(lP + rows * KSPLIT);
    short* Mlo  = Mhi + mElems;
    short* Vt   = Mlo + mElems;

    split_m<<<(int)(mElems / 1024), 256, 0, stream>>>(
        (const float4*)M, (ushort4*)Mhi, (ushort4*)Mlo);
    xw_transpose<<<dim3(SLEN / 64, BATCH), 256, 0, stream>>>(
        X, (const float4*)W, (float4*)Vf, Vt);

    attn_mfma<<<dim3(SLEN / 64 * BATCH * KSPLIT), 256, 0, stream>>>(
        Mhi, Mlo, Vt, accP, lP);

    combine_kernel<<<(int)(vElems / 1024), 256, 0, stream>>>(
        (const float4*)Vf, (const float4*)accP, lP, (const float4*)bias,
        (float4*)out);
}

// Round 6
// 120.127 us; speedup vs baseline: 1.5158x; 1.5158x over previous
//
#include <hip/hip_runtime.h>
#include <cstdint>

#define BATCH  4
#define SLEN   4096
#define FDIM   64
#define KDIM   32
#define KSPLIT 8
#define CHUNK  (SLEN / KSPLIT)   // 512

typedef __attribute__((ext_vector_type(8))) short bf16x8;
typedef __attribute__((ext_vector_type(4))) short bf16x4;
typedef __attribute__((ext_vector_type(4))) float f32x4;

static __device__ __forceinline__ short f2bf(float f) {
    union { float f; unsigned u; } v; v.f = f;
    unsigned r = v.u + 0x7fffu + ((v.u >> 16) & 1u);   // RNE
    return (short)(r >> 16);
}
static __device__ __forceinline__ float bf2f(short s) {
    union { unsigned u; float f; } v;
    v.u = ((unsigned)(unsigned short)s) << 16;
    return v.f;
}
// pack2bf(a,b) -> uint, low short = bf16(a), high short = bf16(b), RNE.
static __device__ __forceinline__ unsigned pack2bf(float a, float b) {
    union { float f; unsigned u; } x, y; x.f = a; y.f = b;
    unsigned ra = x.u + 0x7fffu + ((x.u >> 16) & 1u);
    unsigned rb = y.u + 0x7fffu + ((y.u >> 16) & 1u);
    return __builtin_amdgcn_perm(rb, ra, 0x07060302u);  // {rb.hi, ra.hi}
}

// ---------------------------------------------------------------------------
// Fused prep: (a) M -> bf16 hi/lo Dekker split, (b) V = X@W (fp32),
// (c) Vt[b][f][s] = bf16(V[b][s][f])  (natural key order).
// Grid (64, 4), 256 threads.
// ---------------------------------------------------------------------------
__global__ __launch_bounds__(256) void prep(const float4* __restrict__ M4,
                                            ushort4* __restrict__ H4,
                                            ushort4* __restrict__ L4,
                                            const float* __restrict__ X,
                                            const float4* __restrict__ W4,
                                            float4* __restrict__ V4,
                                            short* __restrict__ Vt) {
    const int blk = blockIdx.y * gridDim.x + blockIdx.x;   // 0..255
    // --- (a) split M: 2 float4 per thread ---
#pragma unroll
    for (int r = 0; r < 2; ++r) {
        int i = (blk * 2 + r) * 256 + threadIdx.x;         // [0, 131072)
        float4 m = M4[i];
        ushort4 h, l;
        h.x = (unsigned short)f2bf(m.x); l.x = (unsigned short)f2bf(m.x - bf2f((short)h.x));
        h.y = (unsigned short)f2bf(m.y); l.y = (unsigned short)f2bf(m.y - bf2f((short)h.y));
        h.z = (unsigned short)f2bf(m.z); l.z = (unsigned short)f2bf(m.z - bf2f((short)h.z));
        h.w = (unsigned short)f2bf(m.w); l.w = (unsigned short)f2bf(m.w - bf2f((short)h.w));
        H4[i] = h; L4[i] = l;
    }
    // --- (b)+(c) XW + transpose ---
    __shared__ float t[64][65];
    const int b  = blockIdx.y;
    const int s0 = blockIdx.x * 64;
    const int o4 = threadIdx.x & 15;
    const int rq = threadIdx.x >> 4;
#pragma unroll
    for (int half = 0; half < 4; ++half) {
        int r = half * 16 + rq;
        const float* __restrict__ xr = X + ((size_t)b * SLEN + s0 + r) * FDIM;
        float4 acc = make_float4(0.f, 0.f, 0.f, 0.f);
#pragma unroll
        for (int f = 0; f < FDIM; ++f) {
            float4 w = W4[f * 16 + o4];
            float  x = xr[f];
            acc.x = fmaf(x, w.x, acc.x);
            acc.y = fmaf(x, w.y, acc.y);
            acc.z = fmaf(x, w.z, acc.z);
            acc.w = fmaf(x, w.w, acc.w);
        }
        V4[((size_t)b * SLEN + s0 + r) * 16 + o4] = acc;
        t[r][o4 * 4 + 0] = acc.x;
        t[r][o4 * 4 + 1] = acc.y;
        t[r][o4 * 4 + 2] = acc.z;
        t[r][o4 * 4 + 3] = acc.w;
    }
    __syncthreads();
    const int c0 = threadIdx.x & 63;
    const int r0 = threadIdx.x >> 6;
#pragma unroll
    for (int i = 0; i < 16; ++i) {
        int f = r0 + i * 4;
        Vt[((size_t)b * FDIM + f) * SLEN + s0 + c0] = f2bf(t[c0][f]);
    }
}

// ---------------------------------------------------------------------------
// Attention partials. Block = 4 waves = 128 queries (32 q / wave, QT=2).
// Per 32-key step: K-hi/K-lo/V staged once into LDS (padded rows, 80 B) and
// consumed by all 4 waves -> per-wave global traffic /4.
// QK computed operand-SWAPPED (A=K, B=Q) so C = [key][q]: lane (col=q, quad)
// holds keys quad*4+j -- exactly the PV A-operand k-slots (two 16-key tiles
// concatenate to k=quad*8+j). No LDS round-trip for P. V B-frags use the
// matching key permutation: two b64 reads per fg from natural-order rows.
// Additive partials: p = exp(relu(s)) raw (max s ~72 < fp32 overflow).
// ---------------------------------------------------------------------------
__global__ __launch_bounds__(256, 3) void attn_mfma(const short* __restrict__ Mhi,
                                                    const short* __restrict__ Mlo,
                                                    const short* __restrict__ Vt,
                                                    float* __restrict__ accP,
                                                    float* __restrict__ lP) {
    const int bid  = blockIdx.x;                 // 1024 blocks
    const int slab = (bid & 7) + 8 * (bid >> 8); // (b,ks) id, XCD-local
    const int qblk = (bid >> 3) & 31;
    const int b    = slab >> 3;
    const int ks   = slab & 7;

    const int tid  = threadIdx.x;
    const int wave = tid >> 6;
    const int lane = tid & 63;
    const int col  = lane & 15;
    const int quad = lane >> 4;
    const int qbase = qblk * 128 + wave * 32;
    const int k0    = ks * CHUNK;

    const short* __restrict__ Mbh = Mhi + (size_t)b * SLEN * KDIM;
    const short* __restrict__ Mbl = Mlo + (size_t)b * SLEN * KDIM;
    const short* __restrict__ Vb  = Vt  + (size_t)b * FDIM * SLEN;

    __shared__ short khi[32 * 40];               // key rows, 80 B stride
    __shared__ short klo[32 * 40];
    __shared__ short vsh[64 * 40];               // f rows,   80 B stride

    // Q fragments (B-operand: n = q = col, k = quad*8+j).
    bf16x8 Qh[2], Ql[2];
#pragma unroll
    for (int tq = 0; tq < 2; ++tq) {
        int qo = (qbase + tq * 16 + col) * KDIM + quad * 8;
        Qh[tq] = *(const bf16x8*)(Mbh + qo);
        Ql[tq] = *(const bf16x8*)(Mbl + qo);
    }

    f32x4 accf[2][4];
#pragma unroll
    for (int tq = 0; tq < 2; ++tq)
#pragma unroll
        for (int fg = 0; fg < 4; ++fg) accf[tq][fg] = (f32x4){0.f, 0.f, 0.f, 0.f};
    float lacc[2] = {0.f, 0.f};

    // Staging roles: tid<128 -> khi (rows 0..31), tid>=128 -> klo; all -> vsh.
    const int krow  = (tid & 127) >> 2;
    const int kpart = tid & 3;
    const int vrow  = tid >> 2;                  // 0..63
    const short* __restrict__ Msrc = (tid < 128) ? Mbh : Mbl;
    short* __restrict__ kdst = (tid < 128) ? khi : klo;

#pragma unroll 1
    for (int kt = k0; kt < k0 + CHUNK; kt += 32) {
        // Global loads first (overlap with previous step's compute).
        bf16x8 kstg = *(const bf16x8*)(Msrc + (kt + krow) * KDIM + kpart * 8);
        bf16x8 vstg = *(const bf16x8*)(Vb + (size_t)vrow * SLEN + kt + kpart * 8);
        __syncthreads();                         // WAR vs previous consumers
        *(bf16x8*)(kdst + krow * 40 + kpart * 8) = kstg;
        *(bf16x8*)(vsh + vrow * 40 + kpart * 8)  = vstg;
        __syncthreads();                         // RAW

        // K A-frags (m = key = col within 16-tile).
        bf16x8 Kh0 = *(const bf16x8*)(khi + col * 40 + quad * 8);
        bf16x8 Kh1 = *(const bf16x8*)(khi + (16 + col) * 40 + quad * 8);
        bf16x8 Kl0 = *(const bf16x8*)(klo + col * 40 + quad * 8);
        bf16x8 Kl1 = *(const bf16x8*)(klo + (16 + col) * 40 + quad * 8);

        // V B-frags: element j<4 = key quad*4+j, j>=4 = key 16+quad*4+(j-4).
        bf16x8 Vv[4];
#pragma unroll
        for (int fg = 0; fg < 4; ++fg) {
            const short* vp = vsh + (fg * 16 + col) * 40 + quad * 4;
            bf16x4 vlo = *(const bf16x4*)(vp);
            bf16x4 vhi = *(const bf16x4*)(vp + 16);
            Vv[fg] = __builtin_shufflevector(vlo, vhi, 0, 1, 2, 3, 4, 5, 6, 7);
        }

#pragma unroll
        for (int tq = 0; tq < 2; ++tq) {
            f32x4 z = (f32x4){0.f, 0.f, 0.f, 0.f};
            f32x4 c0 = __builtin_amdgcn_mfma_f32_16x16x32_bf16(Kh0, Ql[tq], z, 0, 0, 0);
            f32x4 c1 = __builtin_amdgcn_mfma_f32_16x16x32_bf16(Kh1, Ql[tq], z, 0, 0, 0);
            c0 = __builtin_amdgcn_mfma_f32_16x16x32_bf16(Kl0, Qh[tq], c0, 0, 0, 0);
            c1 = __builtin_amdgcn_mfma_f32_16x16x32_bf16(Kl1, Qh[tq], c1, 0, 0, 0);
            c0 = __builtin_amdgcn_mfma_f32_16x16x32_bf16(Kh0, Qh[tq], c0, 0, 0, 0);
            c1 = __builtin_amdgcn_mfma_f32_16x16x32_bf16(Kh1, Qh[tq], c1, 0, 0, 0);

            float e00 = __expf(fmaxf(c0[0], 0.f));
            float e01 = __expf(fmaxf(c0[1], 0.f));
            float e02 = __expf(fmaxf(c0[2], 0.f));
            float e03 = __expf(fmaxf(c0[3], 0.f));
            float e10 = __expf(fmaxf(c1[0], 0.f));
            float e11 = __expf(fmaxf(c1[1], 0.f));
            float e12 = __expf(fmaxf(c1[2], 0.f));
            float e13 = __expf(fmaxf(c1[3], 0.f));
            lacc[tq] += ((e00 + e01) + (e02 + e03)) + ((e10 + e11) + (e12 + e13));

            union { unsigned u[4]; bf16x8 v; } pa;
            pa.u[0] = pack2bf(e00, e01);
            pa.u[1] = pack2bf(e02, e03);
            pa.u[2] = pack2bf(e10, e11);
            pa.u[3] = pack2bf(e12, e13);

#pragma unroll
            for (int fg = 0; fg < 4; ++fg)
                accf[tq][fg] = __builtin_amdgcn_mfma_f32_16x16x32_bf16(
                    pa.v, Vv[fg], accf[tq][fg], 0, 0, 0);
        }
    }

    // Epilogue: C[m=q][n=f]: row q = quad*4+j, col f = fg*16+col.
#pragma unroll
    for (int tq = 0; tq < 2; ++tq) {
#pragma unroll
        for (int j = 0; j < 4; ++j) {
            int q = qbase + tq * 16 + quad * 4 + j;
            size_t base = ((size_t)b * SLEN + q) * KSPLIT + ks;
            float* __restrict__ op = accP + base * FDIM;
#pragma unroll
            for (int fg = 0; fg < 4; ++fg)
                op[fg * 16 + col] = accf[tq][fg][j];
        }
        float lv = lacc[tq];
        lv += __shfl_xor(lv, 16);
        lv += __shfl_xor(lv, 32);
        if (quad == 0) {
            int q = qbase + tq * 16 + col;
            lP[((size_t)b * SLEN + q) * KSPLIT + ks] = lv;
        }
    }
}

// ---------------------------------------------------------------------------
// out = V + (sum acc_i)/(sum l_i) + bias, float4.
// ---------------------------------------------------------------------------
__global__ __launch_bounds__(256) void combine_kernel(const float4* __restrict__ V4,
                                                      const float4* __restrict__ accP4,
                                                      const float* __restrict__ lP,
                                                      const float4* __restrict__ bias4,
                                                      float4* __restrict__ out4) {
    int i  = blockIdx.x * 256 + threadIdx.x;     // [0, B*S*16)
    int o4 = i & 15;
    int row = i >> 4;
    float nx = 0.f, ny = 0.f, nz = 0.f, nw = 0.f, den = 0.f;
#pragma unroll
    for (int k = 0; k < KSPLIT; ++k) {
        float4 a = accP4[((size_t)row * KSPLIT + k) * 16 + o4];
        nx += a.x; ny += a.y; nz += a.z; nw += a.w;
        den += lP[(size_t)row * KSPLIT + k];
    }
    float r = 1.f / den;
    float4 v = V4[i];
    float4 bb = bias4[o4];
    float4 o;
    o.x = v.x + nx * r + bb.x;
    o.y = v.y + ny * r + bb.y;
    o.z = v.z + nz * r + bb.z;
    o.w = v.w + nw * r + bb.w;
    out4[i] = o;
}

// ---------------------------------------------------------------------------
extern "C" void kernel_launch(void* const* d_in, const int* in_sizes, int n_in,
                              void* d_out, int out_size, void* d_ws, size_t ws_size,
                              hipStream_t stream) {
    const float* X    = (const float*)d_in[0];   // [4,4096,64]
    const float* M    = (const float*)d_in[1];   // [4,4096,32]
    const float* W    = (const float*)d_in[2];   // [64,64]
    const float* bias = (const float*)d_in[3];   // [64]
    float* out = (float*)d_out;                  // [4,4096,64]

    const size_t vElems = (size_t)BATCH * SLEN * FDIM;   // 1,048,576
    const size_t mElems = (size_t)BATCH * SLEN * KDIM;   //   524,288
    const size_t rows   = (size_t)BATCH * SLEN;          //    16,384

    float* Vf   = (float*)d_ws;
    float* accP = Vf + vElems;
    float* lP   = accP + vElems * KSPLIT;
    short* Mhi  = (short*)(lP + rows * KSPLIT);
    short* Mlo  = Mhi + mElems;
    short* Vt   = Mlo + mElems;

    prep<<<dim3(SLEN / 64, BATCH), 256, 0, stream>>>(
        (const float4*)M, (ushort4*)Mhi, (ushort4*)Mlo,
        X, (const float4*)W, (float4*)Vf, Vt);

    attn_mfma<<<dim3((SLEN / 128) * BATCH * KSPLIT), 256, 0, stream>>>(
        Mhi, Mlo, Vt, accP, lP);

    combine_kernel<<<(int)(vElems / 1024), 256, 0, stream>>>(
        (const float4*)Vf, (const float4*)accP, lP, (const float4*)bias,
        (float4*)out);
}